// Round 9
// baseline (1773.705 us; speedup 1.0000x reference)
//
#include <hip/hip_runtime.h>
#include <hip/hip_cooperative_groups.h>
#include <hip/hip_bf16.h>

namespace cg = cooperative_groups;

#define NN 50000
#define NE 600000
#define NG 1000
#define IND 16
#define HID 128
#define DESCD 17
#define NL 3
#define BN_EPS 1e-5f
#define NCH 196    // ceil(NN/256)
#define NTILE 782  // ceil(NN/64)

typedef short s16x8 __attribute__((ext_vector_type(8)));
typedef float f32x4 __attribute__((ext_vector_type(4)));
typedef float f32x2 __attribute__((ext_vector_type(2)));
typedef __hip_bfloat16 bfp16;
typedef __hip_bfloat162 bfp162;

struct Prm {
    const float* x; const int* src; const int* dst; const float* ea;
    const int* batch; const float* mol;
    const float* Wp; const float* bp;
    const float* W1; const float* b1; const float* W2; const float* b2;
    const float* gamma; const float* beta; const float* Wf; const float* bf;
    float* out;
    bfp16* h; bfp16* z; bfp16* z2; bfp16* Wt;
    int2* perm; int* rowptr; int* cursor; int* partials; int* poffs; int* deg;
    float* stats3; bfp162* eab2;
};

__global__ void __launch_bounds__(256, 2) mega(Prm p) {
    __shared__ __align__(16) short sW1[16384];  // 32 KB
    __shared__ __align__(16) short sW2[16384];  // 32 KB
    __shared__ __align__(16) short sA[8192];    // 16 KB
    cg::grid_group gg = cg::this_grid();
    const int t = threadIdx.x;
    const int bid = blockIdx.x;
    const int nthr = gridDim.x * 256;
    const int gtid = bid * 256 + t;

    // ---- P0: zero deg + stats ----
    for (int i = gtid; i < NN; i += nthr) p.deg[i] = 0;
    for (int i = gtid; i < 3 * 256; i += nthr) p.stats3[i] = 0.f;
    gg.sync();

    // ---- P1: hist + proj + wprep (independent) ----
    for (int e = gtid; e < NE; e += nthr) atomicAdd(&p.deg[p.dst[e]], 1);
    for (int idx = gtid; idx < NN * HID; idx += nthr) {
        int row = idx >> 7, col = idx & 127;
        const float* xr = p.x + (size_t)row * IND;
        float acc = p.bp[col];
#pragma unroll
        for (int k = 0; k < IND; k++) acc += xr[k] * p.Wp[k * HID + col];
        p.h[idx] = __float2bfloat16(acc);
    }
    for (int id = gtid; id < 6 * HID * HID; id += nthr) {
        int m = id >> 14, rem = id & 16383, n = rem >> 7, k = rem & 127;
        const float* Wsrc = (m < 3) ? (p.W1 + (size_t)m * HID * HID)
                                    : (p.W2 + (size_t)(m - 3) * HID * HID);
        p.Wt[id] = __float2bfloat16(Wsrc[k * HID + n]);
    }
    gg.sync();

    // ---- P2a: per-chunk exclusive scan of deg ----
    int* shi = (int*)sA;
    if (bid < NCH) {
        int i = bid * 256 + t;
        int v = (i < NN) ? p.deg[i] : 0;
        shi[t] = v;
        __syncthreads();
        for (int o = 1; o < 256; o <<= 1) {
            int tmp = (t >= o) ? shi[t - o] : 0;
            __syncthreads();
            shi[t] += tmp;
            __syncthreads();
        }
        if (i < NN) p.rowptr[i] = shi[t] - v;
        if (t == 255) p.partials[bid] = shi[255];
    }
    gg.sync();
    // ---- P2b: block 0 scans partials ----
    if (bid == 0) {
        int v = (t < NCH) ? p.partials[t] : 0;
        shi[t] = v;
        __syncthreads();
        for (int o = 1; o < 256; o <<= 1) {
            int tmp = (t >= o) ? shi[t - o] : 0;
            __syncthreads();
            shi[t] += tmp;
            __syncthreads();
        }
        if (t < NCH) p.poffs[t] = shi[t] - v;
    }
    gg.sync();
    // ---- P2c: add block offsets -> rowptr, cursor ----
    if (bid < NCH) {
        int i = bid * 256 + t;
        if (i < NN) {
            int r = p.rowptr[i] + p.poffs[bid];
            p.rowptr[i] = r;
            p.cursor[i] = r;
            if (i == NN - 1) p.rowptr[NN] = r + p.deg[i];
        }
    }
    gg.sync();

    // ---- P3: fill CSR ----
    for (int e = gtid; e < NE; e += nthr) {
        int pos = atomicAdd(&p.cursor[p.dst[e]], 1);
        p.perm[pos] = make_int2(e, p.src[e]);
    }
    gg.sync();

    const int wid = gtid >> 6, lane = t & 63, nw = nthr >> 6;
    const int f = lane * 2;
    // mlp per-wave constants
    const int w = t >> 6;
    const int l15 = lane & 15, lhi = lane >> 4;
    const int arow = (w << 4) + l15;
    const int abase = arow * 128, asw = arow & 7;
    const int bsw = l15 & 7;

    for (int l = 0; l < NL; l++) {
        // ---- P4: aggr (z[n] = H(n) + sum relu(H(src)+e)), BN of prev layer inline
        {
            const bfp16* hz = (l == 0) ? p.h : p.z2;
            const float* stats = p.stats3 + (l > 0 ? (l - 1) * 256 : 0);
            const float* gam = p.gamma + (l > 0 ? (l - 1) * HID : 0);
            const float* bet = p.beta + (l > 0 ? (l - 1) * HID : 0);
            float sc0 = 0.f, sf0 = 0.f, sc1 = 0.f, sf1 = 0.f;
            if (l > 0) {
                const float invn = 1.f / NN;
                float m0 = stats[f] * invn;
                float v0 = stats[128 + f] * invn - m0 * m0;
                sc0 = rsqrtf(v0 + BN_EPS) * gam[f];
                sf0 = bet[f] - m0 * sc0;
                float m1 = stats[f + 1] * invn;
                float v1 = stats[128 + f + 1] * invn - m1 * m1;
                sc1 = rsqrtf(v1 + BN_EPS) * gam[f + 1];
                sf1 = bet[f + 1] - m1 * sc1;
            }
            for (int n = wid; n < NN; n += nw) {
                int beg = p.rowptr[n], end = p.rowptr[n + 1];
                float ax = 0.f, ay = 0.f;
                int i = beg;
                for (; i + 3 < end; i += 4) {
#pragma unroll
                    for (int u = 0; u < 4; u++) {
                        int2 pr = p.perm[i + u];
                        float2 a;
                        if (l == 0) {
                            f32x2 av = __builtin_nontemporal_load(
                                (const f32x2*)&p.ea[(size_t)pr.x * HID + f]);
                            a = make_float2(av.x, av.y);
                            p.eab2[(size_t)(i + u) * 64 + lane] = __float22bfloat162_rn(a);
                        } else {
                            a = __bfloat1622float2(p.eab2[(size_t)(i + u) * 64 + lane]);
                        }
                        float2 hv = __bfloat1622float2(
                            *(const bfp162*)&hz[(size_t)pr.y * HID + f]);
                        if (l > 0) {
                            hv.x = fmaxf(hv.x * sc0 + sf0, 0.f);
                            hv.y = fmaxf(hv.y * sc1 + sf1, 0.f);
                        }
                        ax += fmaxf(a.x + hv.x, 0.f);
                        ay += fmaxf(a.y + hv.y, 0.f);
                    }
                }
                for (; i < end; i++) {
                    int2 pr = p.perm[i];
                    float2 a;
                    if (l == 0) {
                        f32x2 av = __builtin_nontemporal_load(
                            (const f32x2*)&p.ea[(size_t)pr.x * HID + f]);
                        a = make_float2(av.x, av.y);
                        p.eab2[(size_t)i * 64 + lane] = __float22bfloat162_rn(a);
                    } else {
                        a = __bfloat1622float2(p.eab2[(size_t)i * 64 + lane]);
                    }
                    float2 hv = __bfloat1622float2(
                        *(const bfp162*)&hz[(size_t)pr.y * HID + f]);
                    if (l > 0) {
                        hv.x = fmaxf(hv.x * sc0 + sf0, 0.f);
                        hv.y = fmaxf(hv.y * sc1 + sf1, 0.f);
                    }
                    ax += fmaxf(a.x + hv.x, 0.f);
                    ay += fmaxf(a.y + hv.y, 0.f);
                }
                float2 hn = __bfloat1622float2(*(const bfp162*)&hz[(size_t)n * HID + f]);
                if (l > 0) {
                    hn.x = fmaxf(hn.x * sc0 + sf0, 0.f);
                    hn.y = fmaxf(hn.y * sc1 + sf1, 0.f);
                }
                *(bfp162*)&p.z[(size_t)n * HID + f] =
                    __float22bfloat162_rn(make_float2(ax + hn.x, ay + hn.y));
            }
        }
        gg.sync();

        // ---- P5: fused MLP over row tiles ----
        {
            const short* W1g = (const short*)(p.Wt + (size_t)l * HID * HID);
            const short* W2g = (const short*)(p.Wt + (size_t)(3 + l) * HID * HID);
            const float* b1l = p.b1 + l * HID;
            const float* b2l = p.b2 + l * HID;
            float* statsl = p.stats3 + l * 256;
            // stage both weight matrices once per layer (swizzled)
            for (int g = t; g < 2048; g += 256) {
                int nrow = g >> 4, s = g & 15;
                int sw = nrow * 128 + ((s ^ (nrow & 7)) << 3);
                *(float4*)&sW1[sw] = *(const float4*)&W1g[g * 8];
                *(float4*)&sW2[sw] = *(const float4*)&W2g[g * 8];
            }
            const short* Ag = (const short*)p.z;
            for (int tile = bid; tile < NTILE; tile += gridDim.x) {
                int rowBase = tile * 64;
                __syncthreads();  // weights staged / prev iter LDS reads done
                for (int g = t; g < 1024; g += 256) {
                    int r = g >> 4, s = g & 15;
                    float4 v = make_float4(0.f, 0.f, 0.f, 0.f);
                    if (rowBase + r < NN)
                        v = *(const float4*)&Ag[(size_t)(rowBase + r) * 128 + s * 8];
                    *(float4*)&sA[r * 128 + ((s ^ (r & 7)) << 3)] = v;
                }
                __syncthreads();

                // phase 1: y1 = A @ W1
                f32x4 acc[8];
#pragma unroll
                for (int c = 0; c < 8; c++) acc[c] = (f32x4){0.f, 0.f, 0.f, 0.f};
#pragma unroll
                for (int kk = 0; kk < 4; kk++) {
                    int kslot = kk * 4 + lhi;
                    s16x8 af = *(const s16x8*)&sA[abase + ((kslot ^ asw) << 3)];
#pragma unroll
                    for (int c = 0; c < 8; c++) {
                        s16x8 bfr = *(const s16x8*)&sW1[(c * 16 + l15) * 128 +
                                                        ((kslot ^ bsw) << 3)];
                        acc[c] = __builtin_amdgcn_mfma_f32_16x16x32_bf16(af, bfr, acc[c],
                                                                         0, 0, 0);
                    }
                }
                __syncthreads();
                {
                    const int rowb = (w << 4);
#pragma unroll
                    for (int c = 0; c < 8; c++) {
                        float bb = b1l[c * 16 + l15];
                        int col = c * 16 + l15;
#pragma unroll
                        for (int r = 0; r < 4; r++) {
                            int row = rowb + lhi * 4 + r;
                            float v = fmaxf(acc[c][r] + bb, 0.f);
                            bfp16 bv = __float2bfloat16(v);
                            sA[row * 128 + ((((col >> 3)) ^ (row & 7)) << 3) + (col & 7)] =
                                *reinterpret_cast<short*>(&bv);
                        }
                    }
                }
                __syncthreads();

                // phase 2: z2 = y1 @ W2
                f32x4 acc2[8];
#pragma unroll
                for (int c = 0; c < 8; c++) acc2[c] = (f32x4){0.f, 0.f, 0.f, 0.f};
#pragma unroll
                for (int kk = 0; kk < 4; kk++) {
                    int kslot = kk * 4 + lhi;
                    s16x8 af = *(const s16x8*)&sA[abase + ((kslot ^ asw) << 3)];
#pragma unroll
                    for (int c = 0; c < 8; c++) {
                        s16x8 bfr = *(const s16x8*)&sW2[(c * 16 + l15) * 128 +
                                                        ((kslot ^ bsw) << 3)];
                        acc2[c] = __builtin_amdgcn_mfma_f32_16x16x32_bf16(af, bfr, acc2[c],
                                                                          0, 0, 0);
                    }
                }

                // epilogue: store z2 + column sums
                const int rb = rowBase + (w << 4) + lhi * 4;
                float scol[8], qcol[8];
#pragma unroll
                for (int c = 0; c < 8; c++) {
                    float bb = b2l[c * 16 + l15];
                    float s = 0.f, q = 0.f;
#pragma unroll
                    for (int r = 0; r < 4; r++) {
                        int row = rb + r;
                        float v = acc2[c][r] + bb;
                        if (row < NN) {
                            p.z2[(size_t)row * 128 + c * 16 + l15] = __float2bfloat16(v);
                            s += v;
                            q += v * v;
                        }
                    }
                    scol[c] = s;
                    qcol[c] = q;
                }
#pragma unroll
                for (int c = 0; c < 8; c++) {
                    scol[c] += __shfl_xor(scol[c], 16);
                    scol[c] += __shfl_xor(scol[c], 32);
                    qcol[c] += __shfl_xor(qcol[c], 16);
                    qcol[c] += __shfl_xor(qcol[c], 32);
                }
                __syncthreads();
                float* sStat = (float*)sA;
                if (lane < 16) {
#pragma unroll
                    for (int c = 0; c < 8; c++) {
                        sStat[w * 256 + c * 16 + lane] = scol[c];
                        sStat[w * 256 + 128 + c * 16 + lane] = qcol[c];
                    }
                }
                __syncthreads();
                if (t < 128) {
                    float ss = sStat[t] + sStat[256 + t] + sStat[512 + t] + sStat[768 + t];
                    float qq = sStat[128 + t] + sStat[384 + t] + sStat[640 + t] +
                               sStat[896 + t];
                    atomicAdd(&statsl[t], ss);
                    atomicAdd(&statsl[128 + t], qq);
                }
            }
        }
        gg.sync();
    }

    // ---- P6: final: BN(z2) -> per-graph mean pool -> dot ----
    {
        const float* stats = p.stats3 + 2 * 256;
        const float* gam = p.gamma + 2 * HID;
        const float* bet = p.beta + 2 * HID;
        const float invn = 1.f / NN;
        float m0 = stats[f] * invn;
        float v0 = stats[128 + f] * invn - m0 * m0;
        float sc0 = rsqrtf(v0 + BN_EPS) * gam[f];
        float sf0 = bet[f] - m0 * sc0;
        float m1 = stats[f + 1] * invn;
        float v1 = stats[128 + f + 1] * invn - m1 * m1;
        float sc1 = rsqrtf(v1 + BN_EPS) * gam[f + 1];
        float sf1 = bet[f + 1] - m1 * sc1;

        for (int g = wid; g < NG; g += nw) {
            int lo = 0, hi = NN;
            while (lo < hi) {
                int m = (lo + hi) >> 1;
                if (p.batch[m] < g) lo = m + 1; else hi = m;
            }
            int lb = lo;
            hi = NN;
            while (lo < hi) {
                int m = (lo + hi) >> 1;
                if (p.batch[m] <= g) lo = m + 1; else hi = m;
            }
            int cnt = lo - lb;
            float sx = 0.f, sy = 0.f;
            for (int n = lb; n < lo; n++) {
                float2 v = __bfloat1622float2(*(const bfp162*)&p.z2[(size_t)n * HID + f]);
                sx += fmaxf(v.x * sc0 + sf0, 0.f);
                sy += fmaxf(v.y * sc1 + sf1, 0.f);
            }
            float inv = 1.f / fmaxf((float)cnt, 1.f);
            float acc = sx * inv * p.Wf[f] + sy * inv * p.Wf[f + 1];
            if (lane < DESCD) acc += p.mol[(size_t)g * DESCD + lane] * p.Wf[HID + lane];
#pragma unroll
            for (int o = 32; o > 0; o >>= 1) acc += __shfl_down(acc, o);
            if (lane == 0) p.out[g] = acc + p.bf[0];
        }
    }
}

extern "C" void kernel_launch(void* const* d_in, const int* in_sizes, int n_in,
                              void* d_out, int out_size, void* d_ws, size_t ws_size,
                              hipStream_t stream) {
    const float* x     = (const float*)d_in[0];
    const int*   ei    = (const int*)d_in[1];
    const float* ea    = (const float*)d_in[2];
    const int*   batch = (const int*)d_in[3];
    const float* mol   = (const float*)d_in[4];
    const float* Wp    = (const float*)d_in[5];
    const float* bp    = (const float*)d_in[6];
    const float* W1    = (const float*)d_in[7];
    const float* b1    = (const float*)d_in[8];
    const float* W2    = (const float*)d_in[9];
    const float* b2    = (const float*)d_in[10];
    const float* gamma = (const float*)d_in[11];
    const float* beta  = (const float*)d_in[12];
    const float* Wf    = (const float*)d_in[13];
    const float* bf_   = (const float*)d_in[14];

    char* p = (char*)d_ws;
    size_t off = 0;
    auto alloc = [&](size_t bytes) {
        char* q = p + off;
        off = (off + bytes + 255) & ~(size_t)255;
        return q;
    };
    Prm prm;
    prm.x = x; prm.src = ei; prm.dst = ei + NE; prm.ea = ea;
    prm.batch = batch; prm.mol = mol;
    prm.Wp = Wp; prm.bp = bp; prm.W1 = W1; prm.b1 = b1; prm.W2 = W2; prm.b2 = b2;
    prm.gamma = gamma; prm.beta = beta; prm.Wf = Wf; prm.bf = bf_;
    prm.out = (float*)d_out;
    prm.h      = (bfp16*)alloc((size_t)NN * HID * 2);
    prm.z      = (bfp16*)alloc((size_t)NN * HID * 2);
    prm.z2     = (bfp16*)alloc((size_t)NN * HID * 2);
    prm.Wt     = (bfp16*)alloc((size_t)6 * HID * HID * 2);
    prm.perm   = (int2*)alloc((size_t)NE * 8);
    prm.rowptr = (int*)alloc((NN + 16) * 4);
    prm.cursor = (int*)alloc(NN * 4);
    prm.partials = (int*)alloc(NCH * 4);
    prm.poffs    = (int*)alloc(NCH * 4);
    prm.deg      = (int*)alloc(NN * 4);
    prm.stats3   = (float*)alloc(3 * 256 * 4);
    prm.eab2     = (bfp162*)alloc((size_t)NE * HID * 2);

    int occ = 0;
    if (hipOccupancyMaxActiveBlocksPerMultiprocessor(&occ, (const void*)mega, 256, 0)
            != hipSuccess || occ <= 0)
        occ = 2;
    if (occ > 2) occ = 2;
    int grid = occ * 256;

    void* args[] = { &prm };
    (void)hipLaunchCooperativeKernel((const void*)mega, dim3(grid), dim3(256),
                                     args, 0, stream);
}

// Round 11
// 887.549 us; speedup vs baseline: 1.9984x; 1.9984x over previous
//
#include <hip/hip_runtime.h>
#include <hip/hip_cooperative_groups.h>
#include <hip/hip_bf16.h>

namespace cg = cooperative_groups;

#define NN 50000
#define NE 600000
#define NG 1000
#define IND 16
#define HID 128
#define DESCD 17
#define NL 3
#define BN_EPS 1e-5f
#define NCH 196  // ceil(NN/256)

typedef short s16x8 __attribute__((ext_vector_type(8)));
typedef float f32x4 __attribute__((ext_vector_type(4)));
typedef float f32x2 __attribute__((ext_vector_type(2)));
typedef int   i32x4 __attribute__((ext_vector_type(4)));
typedef __hip_bfloat16 bfp16;
typedef __hip_bfloat162 bfp162;

// ---------------- cooperative CSR build (one dispatch) ----------------
struct CsrPrm {
    const int* src; const int* dst;
    int2* perm; int* rowptr; int* cursor; int* partials; int* poffs; int* deg;
    float* stats3;
};

__global__ void __launch_bounds__(256) k_csr(CsrPrm p) {
    __shared__ int sh[256];
    cg::grid_group gg = cg::this_grid();
    const int t = threadIdx.x;
    const int bid = blockIdx.x;
    const int nthr = gridDim.x * 256;
    const int gtid = bid * 256 + t;

    // P0: zero deg + stats
    for (int i = gtid; i < NN; i += nthr) p.deg[i] = 0;
    for (int i = gtid; i < 3 * 256; i += nthr) p.stats3[i] = 0.f;
    gg.sync();
    // P1: histogram
    for (int e = gtid; e < NE; e += nthr) atomicAdd(&p.deg[p.dst[e]], 1);
    gg.sync();
    // P2a: per-chunk scan
    if (bid < NCH) {
        int i = bid * 256 + t;
        int v = (i < NN) ? p.deg[i] : 0;
        sh[t] = v;
        __syncthreads();
        for (int o = 1; o < 256; o <<= 1) {
            int tmp = (t >= o) ? sh[t - o] : 0;
            __syncthreads();
            sh[t] += tmp;
            __syncthreads();
        }
        if (i < NN) p.rowptr[i] = sh[t] - v;
        if (t == 255) p.partials[bid] = sh[255];
    }
    gg.sync();
    // P2b: scan partials
    if (bid == 0) {
        int v = (t < NCH) ? p.partials[t] : 0;
        sh[t] = v;
        __syncthreads();
        for (int o = 1; o < 256; o <<= 1) {
            int tmp = (t >= o) ? sh[t - o] : 0;
            __syncthreads();
            sh[t] += tmp;
            __syncthreads();
        }
        if (t < NCH) p.poffs[t] = sh[t] - v;
    }
    gg.sync();
    // P2c: add offsets
    if (bid < NCH) {
        int i = bid * 256 + t;
        if (i < NN) {
            int r = p.rowptr[i] + p.poffs[bid];
            p.rowptr[i] = r;
            p.cursor[i] = r;
            if (i == NN - 1) p.rowptr[NN] = r + p.deg[i];
        }
    }
    gg.sync();
    // P3: fill
    for (int e = gtid; e < NE; e += nthr) {
        int pos = atomicAdd(&p.cursor[p.dst[e]], 1);
        p.perm[pos] = make_int2(e, p.src[e]);
    }
}

// ---------------- prep: ea->bf16 linear, proj, wprep (one dispatch) --------
__global__ __launch_bounds__(256) void k_prep(const float* __restrict__ ea,
                                              bfp16* __restrict__ eab,
                                              const float* __restrict__ x,
                                              const float* __restrict__ Wp,
                                              const float* __restrict__ bp,
                                              bfp16* __restrict__ h,
                                              const float* __restrict__ W1,
                                              const float* __restrict__ W2,
                                              bfp16* __restrict__ Wt) {
    const size_t nthr = (size_t)gridDim.x * 256;
    const size_t gt = (size_t)blockIdx.x * 256 + threadIdx.x;
    // conv: 8 floats per thread-iter, linear
    const size_t nchunk = (size_t)NE * HID / 8;
    for (size_t i = gt; i < nchunk; i += nthr) {
        const f32x4* s = (const f32x4*)(ea + i * 8);
        f32x4 a = __builtin_nontemporal_load(s);
        f32x4 b = __builtin_nontemporal_load(s + 1);
        bfp162 q0 = __float22bfloat162_rn(make_float2(a.x, a.y));
        bfp162 q1 = __float22bfloat162_rn(make_float2(a.z, a.w));
        bfp162 q2 = __float22bfloat162_rn(make_float2(b.x, b.y));
        bfp162 q3 = __float22bfloat162_rn(make_float2(b.z, b.w));
        i32x4 o;
        o.x = *reinterpret_cast<int*>(&q0);
        o.y = *reinterpret_cast<int*>(&q1);
        o.z = *reinterpret_cast<int*>(&q2);
        o.w = *reinterpret_cast<int*>(&q3);
        __builtin_nontemporal_store(o, (i32x4*)(eab + i * 8));
    }
    // proj
    for (size_t idx = gt; idx < (size_t)NN * HID; idx += nthr) {
        int row = (int)(idx >> 7), col = (int)(idx & 127);
        const float* xr = x + (size_t)row * IND;
        float acc = bp[col];
#pragma unroll
        for (int k = 0; k < IND; k++) acc += xr[k] * Wp[k * HID + col];
        h[idx] = __float2bfloat16(acc);
    }
    // wprep
    for (size_t id = gt; id < 6 * HID * HID; id += nthr) {
        int m = (int)(id >> 14), rem = (int)(id & 16383);
        int n = rem >> 7, k = rem & 127;
        const float* Wsrc = (m < 3) ? (W1 + (size_t)m * HID * HID)
                                    : (W2 + (size_t)(m - 3) * HID * HID);
        Wt[id] = __float2bfloat16(Wsrc[k * HID + n]);
    }
}

// ---------------- gather aggregation (+inline BN of previous layer) -------
// z[n] = H(n) + sum_e relu(H(src)+eab[e]); one wave per node, 2 feats/lane.
// eab read via perm.x (random 256B rows, L3-resident).
template <bool BN>
__global__ __launch_bounds__(256) void k_aggr(const bfp16* __restrict__ hz,
                                              const bfp16* __restrict__ eab,
                                              const int2* __restrict__ perm,
                                              const int* __restrict__ rowptr,
                                              const float* __restrict__ stats,
                                              const float* __restrict__ gamma,
                                              const float* __restrict__ beta,
                                              bfp16* __restrict__ z) {
    int nid = (blockIdx.x * blockDim.x + threadIdx.x) >> 6;
    int lane = threadIdx.x & 63;
    if (nid >= NN) return;
    const int f = lane * 2;

    float sc0 = 0.f, sf0 = 0.f, sc1 = 0.f, sf1 = 0.f;
    if (BN) {
        const float invn = 1.f / NN;
        float m0 = stats[f] * invn;
        float v0 = stats[128 + f] * invn - m0 * m0;
        sc0 = rsqrtf(v0 + BN_EPS) * gamma[f];
        sf0 = beta[f] - m0 * sc0;
        float m1 = stats[f + 1] * invn;
        float v1 = stats[128 + f + 1] * invn - m1 * m1;
        sc1 = rsqrtf(v1 + BN_EPS) * gamma[f + 1];
        sf1 = beta[f + 1] - m1 * sc1;
    }

    int beg = rowptr[nid], end = rowptr[nid + 1];
    float ax = 0.f, ay = 0.f;
    int i = beg;
    for (; i + 3 < end; i += 4) {
#pragma unroll
        for (int u = 0; u < 4; u++) {
            int2 pr = perm[i + u];
            float2 a = __bfloat1622float2(*(const bfp162*)&eab[(size_t)pr.x * HID + f]);
            float2 hv = __bfloat1622float2(*(const bfp162*)&hz[(size_t)pr.y * HID + f]);
            if (BN) {
                hv.x = fmaxf(hv.x * sc0 + sf0, 0.f);
                hv.y = fmaxf(hv.y * sc1 + sf1, 0.f);
            }
            ax += fmaxf(a.x + hv.x, 0.f);
            ay += fmaxf(a.y + hv.y, 0.f);
        }
    }
    for (; i < end; i++) {
        int2 pr = perm[i];
        float2 a = __bfloat1622float2(*(const bfp162*)&eab[(size_t)pr.x * HID + f]);
        float2 hv = __bfloat1622float2(*(const bfp162*)&hz[(size_t)pr.y * HID + f]);
        if (BN) {
            hv.x = fmaxf(hv.x * sc0 + sf0, 0.f);
            hv.y = fmaxf(hv.y * sc1 + sf1, 0.f);
        }
        ax += fmaxf(a.x + hv.x, 0.f);
        ay += fmaxf(a.y + hv.y, 0.f);
    }
    float2 hn = __bfloat1622float2(*(const bfp162*)&hz[(size_t)nid * HID + f]);
    if (BN) {
        hn.x = fmaxf(hn.x * sc0 + sf0, 0.f);
        hn.y = fmaxf(hn.y * sc1 + sf1, 0.f);
    }
    *(bfp162*)&z[(size_t)nid * HID + f] =
        __float22bfloat162_rn(make_float2(ax + hn.x, ay + hn.y));
}

// ---------------- fused MLP: z2 = relu(A@W1+b1)@W2+b2, + BN col sums -------
__global__ __launch_bounds__(256) void k_mlp(const bfp16* __restrict__ A,
                                             const bfp16* __restrict__ Wt1,
                                             const bfp16* __restrict__ Wt2,
                                             const float* __restrict__ b1,
                                             const float* __restrict__ b2,
                                             bfp16* __restrict__ z2,
                                             float* __restrict__ stats,
                                             int N) {
    __shared__ __align__(16) short sW1[128 * 128];
    __shared__ __align__(16) short sW2[128 * 128];
    __shared__ __align__(16) short sA[64 * 128];
    const int t = threadIdx.x;
    const int rowBase = blockIdx.x * 64;

    const short* W1g = (const short*)Wt1;
    const short* W2g = (const short*)Wt2;
    for (int g = t; g < 2048; g += 256) {
        int nrow = g >> 4, s = g & 15;
        int sw = nrow * 128 + ((s ^ (nrow & 7)) << 3);
        *(float4*)&sW1[sw] = *(const float4*)&W1g[g * 8];
        *(float4*)&sW2[sw] = *(const float4*)&W2g[g * 8];
    }
    const short* Ag = (const short*)A;
    for (int g = t; g < 1024; g += 256) {
        int r = g >> 4, s = g & 15;
        float4 v = make_float4(0.f, 0.f, 0.f, 0.f);
        if (rowBase + r < N) v = *(const float4*)&Ag[(size_t)(rowBase + r) * 128 + s * 8];
        *(float4*)&sA[r * 128 + ((s ^ (r & 7)) << 3)] = v;
    }
    __syncthreads();

    const int w = t >> 6, lane = t & 63;
    const int l15 = lane & 15, lhi = lane >> 4;
    const int arow = (w << 4) + l15;
    const int abase = arow * 128, asw = arow & 7;
    const int bsw = l15 & 7;

    f32x4 acc[8];
#pragma unroll
    for (int c = 0; c < 8; c++) acc[c] = (f32x4){0.f, 0.f, 0.f, 0.f};
#pragma unroll
    for (int kk = 0; kk < 4; kk++) {
        int kslot = kk * 4 + lhi;
        s16x8 af = *(const s16x8*)&sA[abase + ((kslot ^ asw) << 3)];
#pragma unroll
        for (int c = 0; c < 8; c++) {
            s16x8 bfr = *(const s16x8*)&sW1[(c * 16 + l15) * 128 + ((kslot ^ bsw) << 3)];
            acc[c] = __builtin_amdgcn_mfma_f32_16x16x32_bf16(af, bfr, acc[c], 0, 0, 0);
        }
    }
    __syncthreads();

    {
        const int rowb = (w << 4);
#pragma unroll
        for (int c = 0; c < 8; c++) {
            float bb = b1[c * 16 + l15];
            int col = c * 16 + l15;
#pragma unroll
            for (int r = 0; r < 4; r++) {
                int row = rowb + lhi * 4 + r;
                float v = fmaxf(acc[c][r] + bb, 0.f);
                bfp16 bv = __float2bfloat16(v);
                sA[row * 128 + ((((col >> 3)) ^ (row & 7)) << 3) + (col & 7)] =
                    *reinterpret_cast<short*>(&bv);
            }
        }
    }
    __syncthreads();

    f32x4 acc2[8];
#pragma unroll
    for (int c = 0; c < 8; c++) acc2[c] = (f32x4){0.f, 0.f, 0.f, 0.f};
#pragma unroll
    for (int kk = 0; kk < 4; kk++) {
        int kslot = kk * 4 + lhi;
        s16x8 af = *(const s16x8*)&sA[abase + ((kslot ^ asw) << 3)];
#pragma unroll
        for (int c = 0; c < 8; c++) {
            s16x8 bfr = *(const s16x8*)&sW2[(c * 16 + l15) * 128 + ((kslot ^ bsw) << 3)];
            acc2[c] = __builtin_amdgcn_mfma_f32_16x16x32_bf16(af, bfr, acc2[c], 0, 0, 0);
        }
    }

    const int rb = rowBase + (w << 4) + lhi * 4;
    float scol[8], qcol[8];
#pragma unroll
    for (int c = 0; c < 8; c++) {
        float bb = b2[c * 16 + l15];
        float s = 0.f, q = 0.f;
#pragma unroll
        for (int r = 0; r < 4; r++) {
            int row = rb + r;
            float v = acc2[c][r] + bb;
            if (row < N) {
                z2[(size_t)row * 128 + c * 16 + l15] = __float2bfloat16(v);
                s += v;
                q += v * v;
            }
        }
        scol[c] = s;
        qcol[c] = q;
    }
#pragma unroll
    for (int c = 0; c < 8; c++) {
        scol[c] += __shfl_xor(scol[c], 16);
        scol[c] += __shfl_xor(scol[c], 32);
        qcol[c] += __shfl_xor(qcol[c], 16);
        qcol[c] += __shfl_xor(qcol[c], 32);
    }
    __syncthreads();
    float* sStat = (float*)sA;
    if (lane < 16) {
#pragma unroll
        for (int c = 0; c < 8; c++) {
            sStat[w * 256 + c * 16 + lane] = scol[c];
            sStat[w * 256 + 128 + c * 16 + lane] = qcol[c];
        }
    }
    __syncthreads();
    if (t < 128) {
        float ss = sStat[t] + sStat[256 + t] + sStat[512 + t] + sStat[768 + t];
        float qq = sStat[128 + t] + sStat[384 + t] + sStat[640 + t] + sStat[896 + t];
        atomicAdd(&stats[t], ss);
        atomicAdd(&stats[128 + t], qq);
    }
}

// ---------------- final: BN(z2) -> per-graph mean pool -> dot --------------
__global__ __launch_bounds__(256) void k_finalpool(const bfp16* __restrict__ z2,
                                                   const float* __restrict__ stats,
                                                   const float* __restrict__ gamma,
                                                   const float* __restrict__ beta,
                                                   const int* __restrict__ batch,
                                                   const float* __restrict__ mol,
                                                   const float* __restrict__ Wf,
                                                   const float* __restrict__ bfp,
                                                   float* __restrict__ out) {
    int gid = (blockIdx.x * blockDim.x + threadIdx.x) >> 6;
    int lane = threadIdx.x & 63;
    if (gid >= NG) return;
    const int f = lane * 2;

    const float invn = 1.f / NN;
    float m0 = stats[f] * invn;
    float v0 = stats[128 + f] * invn - m0 * m0;
    float sc0 = rsqrtf(v0 + BN_EPS) * gamma[f];
    float sf0 = beta[f] - m0 * sc0;
    float m1 = stats[f + 1] * invn;
    float v1 = stats[128 + f + 1] * invn - m1 * m1;
    float sc1 = rsqrtf(v1 + BN_EPS) * gamma[f + 1];
    float sf1 = beta[f + 1] - m1 * sc1;

    int lo = 0, hi = NN;
    while (lo < hi) { int m = (lo + hi) >> 1; if (batch[m] < gid) lo = m + 1; else hi = m; }
    int lb = lo;
    hi = NN;
    while (lo < hi) { int m = (lo + hi) >> 1; if (batch[m] <= gid) lo = m + 1; else hi = m; }
    int cnt = lo - lb;

    float sx = 0.f, sy = 0.f;
    for (int n = lb; n < lo; n++) {
        float2 v = __bfloat1622float2(*(const bfp162*)&z2[(size_t)n * HID + f]);
        sx += fmaxf(v.x * sc0 + sf0, 0.f);
        sy += fmaxf(v.y * sc1 + sf1, 0.f);
    }
    float inv = 1.f / fmaxf((float)cnt, 1.f);
    float acc = sx * inv * Wf[f] + sy * inv * Wf[f + 1];
    if (lane < DESCD) acc += mol[(size_t)gid * DESCD + lane] * Wf[HID + lane];
#pragma unroll
    for (int o = 32; o > 0; o >>= 1) acc += __shfl_down(acc, o);
    if (lane == 0) out[gid] = acc + bfp[0];
}

extern "C" void kernel_launch(void* const* d_in, const int* in_sizes, int n_in,
                              void* d_out, int out_size, void* d_ws, size_t ws_size,
                              hipStream_t stream) {
    const float* x     = (const float*)d_in[0];
    const int*   ei    = (const int*)d_in[1];
    const float* ea    = (const float*)d_in[2];
    const int*   batch = (const int*)d_in[3];
    const float* mol   = (const float*)d_in[4];
    const float* Wp    = (const float*)d_in[5];
    const float* bp    = (const float*)d_in[6];
    const float* W1    = (const float*)d_in[7];
    const float* b1    = (const float*)d_in[8];
    const float* W2    = (const float*)d_in[9];
    const float* b2    = (const float*)d_in[10];
    const float* gamma = (const float*)d_in[11];
    const float* beta  = (const float*)d_in[12];
    const float* Wf    = (const float*)d_in[13];
    const float* bf_   = (const float*)d_in[14];
    float* out = (float*)d_out;

    char* p = (char*)d_ws;
    size_t off = 0;
    auto alloc = [&](size_t bytes) {
        char* q = p + off;
        off = (off + bytes + 255) & ~(size_t)255;
        return q;
    };
    bfp16* h      = (bfp16*)alloc((size_t)NN * HID * 2);
    bfp16* z      = (bfp16*)alloc((size_t)NN * HID * 2);
    bfp16* z2     = (bfp16*)alloc((size_t)NN * HID * 2);
    bfp16* Wt     = (bfp16*)alloc((size_t)6 * HID * HID * 2);
    int2*  perm   = (int2*)alloc((size_t)NE * 8);
    int*   rowptr = (int*)alloc((NN + 16) * 4);
    int*   cursor = (int*)alloc(NN * 4);
    int*   partials = (int*)alloc(NCH * 4);
    int*   poffs    = (int*)alloc(NCH * 4);
    int*   deg      = (int*)alloc(NN * 4);
    float* stats3   = (float*)alloc(3 * 256 * 4);
    bfp16* eab      = (bfp16*)alloc((size_t)NE * HID * 2);

    CsrPrm cp;
    cp.src = ei; cp.dst = ei + NE;
    cp.perm = perm; cp.rowptr = rowptr; cp.cursor = cursor;
    cp.partials = partials; cp.poffs = poffs; cp.deg = deg; cp.stats3 = stats3;

    int occ = 0;
    if (hipOccupancyMaxActiveBlocksPerMultiprocessor(&occ, (const void*)k_csr, 256, 0)
            != hipSuccess || occ <= 0)
        occ = 4;
    int csrGrid = occ * 256;
    if (csrGrid > 784) csrGrid = 784;
    if (csrGrid < NCH) csrGrid = NCH;

    void* args[] = { &cp };
    (void)hipLaunchCooperativeKernel((const void*)k_csr, dim3(csrGrid), dim3(256),
                                     args, 0, stream);

    k_prep<<<9600000 / 256, 256, 0, stream>>>(ea, eab, x, Wp, bp, h, W1, W2, Wt);

    const int aggrGrid = (NN * 64) / 256;
    const int mlpGrid = (NN + 63) / 64;
    for (int l = 0; l < NL; l++) {
        if (l == 0)
            k_aggr<false><<<aggrGrid, 256, 0, stream>>>(
                h, eab, perm, rowptr, nullptr, nullptr, nullptr, z);
        else
            k_aggr<true><<<aggrGrid, 256, 0, stream>>>(
                z2, eab, perm, rowptr, stats3 + (l - 1) * 256,
                gamma + (l - 1) * HID, beta + (l - 1) * HID, z);
        k_mlp<<<mlpGrid, 256, 0, stream>>>(
            z, Wt + (size_t)l * HID * HID, Wt + (size_t)(3 + l) * HID * HID,
            b1 + l * HID, b2 + l * HID, z2, stats3 + l * 256, NN);
    }

    k_finalpool<<<(NG * 64) / 256, 256, 0, stream>>>(
        z2, stats3 + 2 * 256, gamma + 2 * HID, beta + 2 * HID,
        batch, mol, Wf, bf_, out);
}

// Round 12
// 457.721 us; speedup vs baseline: 3.8751x; 1.9391x over previous
//
#include <hip/hip_runtime.h>
#include <hip/hip_bf16.h>

#define NN 50000
#define NE 600000
#define NG 1000
#define IND 16
#define HID 128
#define DESCD 17
#define NL 3
#define BN_EPS 1e-5f
#define NB_SCAN 196  // ceil(NN/256)

typedef short s16x8 __attribute__((ext_vector_type(8)));
typedef float f32x4 __attribute__((ext_vector_type(4)));
typedef int   i32x4 __attribute__((ext_vector_type(4)));
typedef __hip_bfloat16 bfp16;
typedef __hip_bfloat162 bfp162;

// ---------------- CSR build (5 small dispatches; NO grid.sync) -------------
__global__ __launch_bounds__(256) void k_hist(const int* __restrict__ dst,
                                              int* __restrict__ deg) {
    int e = blockIdx.x * blockDim.x + threadIdx.x;
    if (e >= NE) return;
    atomicAdd(&deg[dst[e]], 1);
}

__global__ __launch_bounds__(256) void k_part(const int* __restrict__ deg,
                                              int* __restrict__ partials) {
    __shared__ int sh[256];
    int i = blockIdx.x * 256 + threadIdx.x;
    sh[threadIdx.x] = (i < NN) ? deg[i] : 0;
    __syncthreads();
    for (int o = 128; o > 0; o >>= 1) {
        if (threadIdx.x < o) sh[threadIdx.x] += sh[threadIdx.x + o];
        __syncthreads();
    }
    if (threadIdx.x == 0) partials[blockIdx.x] = sh[0];
}

__global__ __launch_bounds__(256) void k_scanpart(const int* __restrict__ partials,
                                                  int* __restrict__ poffs) {
    __shared__ int sh[256];
    int t = threadIdx.x;
    int v = (t < NB_SCAN) ? partials[t] : 0;
    sh[t] = v;
    __syncthreads();
    for (int o = 1; o < 256; o <<= 1) {
        int tmp = (t >= o) ? sh[t - o] : 0;
        __syncthreads();
        sh[t] += tmp;
        __syncthreads();
    }
    if (t < NB_SCAN) poffs[t] = sh[t] - v;
}

__global__ __launch_bounds__(256) void k_scatter(const int* __restrict__ deg,
                                                 const int* __restrict__ poffs,
                                                 int* __restrict__ rowptr,
                                                 int* __restrict__ cursor) {
    __shared__ int sh[256];
    int b = blockIdx.x, t = threadIdx.x;
    int i = b * 256 + t;
    int v = (i < NN) ? deg[i] : 0;
    sh[t] = v;
    __syncthreads();
    for (int o = 1; o < 256; o <<= 1) {
        int tmp = (t >= o) ? sh[t - o] : 0;
        __syncthreads();
        sh[t] += tmp;
        __syncthreads();
    }
    int excl = sh[t] - v + poffs[b];
    if (i < NN) {
        rowptr[i] = excl;
        cursor[i] = excl;
        if (i == NN - 1) rowptr[NN] = excl + v;
    }
}

__global__ __launch_bounds__(256) void k_fill(const int* __restrict__ src,
                                              const int* __restrict__ dst,
                                              int* __restrict__ cursor,
                                              int2* __restrict__ perm) {
    int e = blockIdx.x * blockDim.x + threadIdx.x;
    if (e >= NE) return;
    int pos = atomicAdd(&cursor[dst[e]], 1);
    perm[pos] = make_int2(e, src[e]);
}

// ---------------- prep: ea->bf16 linear, proj, wprep (one dispatch) --------
__global__ __launch_bounds__(256) void k_prep(const float* __restrict__ ea,
                                              bfp16* __restrict__ eab,
                                              const float* __restrict__ x,
                                              const float* __restrict__ Wp,
                                              const float* __restrict__ bp,
                                              bfp16* __restrict__ h,
                                              const float* __restrict__ W1,
                                              const float* __restrict__ W2,
                                              bfp16* __restrict__ Wt) {
    const size_t nthr = (size_t)gridDim.x * 256;
    const size_t gt = (size_t)blockIdx.x * 256 + threadIdx.x;
    const size_t nchunk = (size_t)NE * HID / 8;
    for (size_t i = gt; i < nchunk; i += nthr) {
        const f32x4* s = (const f32x4*)(ea + i * 8);
        f32x4 a = __builtin_nontemporal_load(s);
        f32x4 b = __builtin_nontemporal_load(s + 1);
        bfp162 q0 = __float22bfloat162_rn(make_float2(a.x, a.y));
        bfp162 q1 = __float22bfloat162_rn(make_float2(a.z, a.w));
        bfp162 q2 = __float22bfloat162_rn(make_float2(b.x, b.y));
        bfp162 q3 = __float22bfloat162_rn(make_float2(b.z, b.w));
        i32x4 o;
        o.x = *reinterpret_cast<int*>(&q0);
        o.y = *reinterpret_cast<int*>(&q1);
        o.z = *reinterpret_cast<int*>(&q2);
        o.w = *reinterpret_cast<int*>(&q3);
        __builtin_nontemporal_store(o, (i32x4*)(eab + i * 8));
    }
    for (size_t idx = gt; idx < (size_t)NN * HID; idx += nthr) {
        int row = (int)(idx >> 7), col = (int)(idx & 127);
        const float* xr = x + (size_t)row * IND;
        float acc = bp[col];
#pragma unroll
        for (int k = 0; k < IND; k++) acc += xr[k] * Wp[k * HID + col];
        h[idx] = __float2bfloat16(acc);
    }
    for (size_t id = gt; id < 6 * HID * HID; id += nthr) {
        int m = (int)(id >> 14), rem = (int)(id & 16383);
        int n = rem >> 7, k = rem & 127;
        const float* Wsrc = (m < 3) ? (W1 + (size_t)m * HID * HID)
                                    : (W2 + (size_t)(m - 3) * HID * HID);
        Wt[id] = __float2bfloat16(Wsrc[k * HID + n]);
    }
}

// ---------------- gather aggregation (+inline BN of previous layer) -------
template <bool BN>
__global__ __launch_bounds__(256) void k_aggr(const bfp16* __restrict__ hz,
                                              const bfp16* __restrict__ eab,
                                              const int2* __restrict__ perm,
                                              const int* __restrict__ rowptr,
                                              const float* __restrict__ stats,
                                              const float* __restrict__ gamma,
                                              const float* __restrict__ beta,
                                              bfp16* __restrict__ z) {
    int nid = (blockIdx.x * blockDim.x + threadIdx.x) >> 6;
    int lane = threadIdx.x & 63;
    if (nid >= NN) return;
    const int f = lane * 2;

    float sc0 = 0.f, sf0 = 0.f, sc1 = 0.f, sf1 = 0.f;
    if (BN) {
        const float invn = 1.f / NN;
        float m0 = stats[f] * invn;
        float v0 = stats[128 + f] * invn - m0 * m0;
        sc0 = rsqrtf(v0 + BN_EPS) * gamma[f];
        sf0 = beta[f] - m0 * sc0;
        float m1 = stats[f + 1] * invn;
        float v1 = stats[128 + f + 1] * invn - m1 * m1;
        sc1 = rsqrtf(v1 + BN_EPS) * gamma[f + 1];
        sf1 = beta[f + 1] - m1 * sc1;
    }

    int beg = rowptr[nid], end = rowptr[nid + 1];
    float ax = 0.f, ay = 0.f;
    int i = beg;
    for (; i + 3 < end; i += 4) {
#pragma unroll
        for (int u = 0; u < 4; u++) {
            int2 pr = perm[i + u];
            float2 a = __bfloat1622float2(*(const bfp162*)&eab[(size_t)pr.x * HID + f]);
            float2 hv = __bfloat1622float2(*(const bfp162*)&hz[(size_t)pr.y * HID + f]);
            if (BN) {
                hv.x = fmaxf(hv.x * sc0 + sf0, 0.f);
                hv.y = fmaxf(hv.y * sc1 + sf1, 0.f);
            }
            ax += fmaxf(a.x + hv.x, 0.f);
            ay += fmaxf(a.y + hv.y, 0.f);
        }
    }
    for (; i < end; i++) {
        int2 pr = perm[i];
        float2 a = __bfloat1622float2(*(const bfp162*)&eab[(size_t)pr.x * HID + f]);
        float2 hv = __bfloat1622float2(*(const bfp162*)&hz[(size_t)pr.y * HID + f]);
        if (BN) {
            hv.x = fmaxf(hv.x * sc0 + sf0, 0.f);
            hv.y = fmaxf(hv.y * sc1 + sf1, 0.f);
        }
        ax += fmaxf(a.x + hv.x, 0.f);
        ay += fmaxf(a.y + hv.y, 0.f);
    }
    float2 hn = __bfloat1622float2(*(const bfp162*)&hz[(size_t)nid * HID + f]);
    if (BN) {
        hn.x = fmaxf(hn.x * sc0 + sf0, 0.f);
        hn.y = fmaxf(hn.y * sc1 + sf1, 0.f);
    }
    *(bfp162*)&z[(size_t)nid * HID + f] =
        __float22bfloat162_rn(make_float2(ax + hn.x, ay + hn.y));
}

// ---------------- fused MLP: z2 = relu(A@W1+b1)@W2+b2, + BN col sums -------
__global__ __launch_bounds__(256) void k_mlp(const bfp16* __restrict__ A,
                                             const bfp16* __restrict__ Wt1,
                                             const bfp16* __restrict__ Wt2,
                                             const float* __restrict__ b1,
                                             const float* __restrict__ b2,
                                             bfp16* __restrict__ z2,
                                             float* __restrict__ stats,
                                             int N) {
    __shared__ __align__(16) short sW1[128 * 128];
    __shared__ __align__(16) short sW2[128 * 128];
    __shared__ __align__(16) short sA[64 * 128];
    const int t = threadIdx.x;
    const int rowBase = blockIdx.x * 64;

    const short* W1g = (const short*)Wt1;
    const short* W2g = (const short*)Wt2;
    for (int g = t; g < 2048; g += 256) {
        int nrow = g >> 4, s = g & 15;
        int sw = nrow * 128 + ((s ^ (nrow & 7)) << 3);
        *(float4*)&sW1[sw] = *(const float4*)&W1g[g * 8];
        *(float4*)&sW2[sw] = *(const float4*)&W2g[g * 8];
    }
    const short* Ag = (const short*)A;
    for (int g = t; g < 1024; g += 256) {
        int r = g >> 4, s = g & 15;
        float4 v = make_float4(0.f, 0.f, 0.f, 0.f);
        if (rowBase + r < N) v = *(const float4*)&Ag[(size_t)(rowBase + r) * 128 + s * 8];
        *(float4*)&sA[r * 128 + ((s ^ (r & 7)) << 3)] = v;
    }
    __syncthreads();

    const int w = t >> 6, lane = t & 63;
    const int l15 = lane & 15, lhi = lane >> 4;
    const int arow = (w << 4) + l15;
    const int abase = arow * 128, asw = arow & 7;
    const int bsw = l15 & 7;

    f32x4 acc[8];
#pragma unroll
    for (int c = 0; c < 8; c++) acc[c] = (f32x4){0.f, 0.f, 0.f, 0.f};
#pragma unroll
    for (int kk = 0; kk < 4; kk++) {
        int kslot = kk * 4 + lhi;
        s16x8 af = *(const s16x8*)&sA[abase + ((kslot ^ asw) << 3)];
#pragma unroll
        for (int c = 0; c < 8; c++) {
            s16x8 bfr = *(const s16x8*)&sW1[(c * 16 + l15) * 128 + ((kslot ^ bsw) << 3)];
            acc[c] = __builtin_amdgcn_mfma_f32_16x16x32_bf16(af, bfr, acc[c], 0, 0, 0);
        }
    }
    __syncthreads();

    {
        const int rowb = (w << 4);
#pragma unroll
        for (int c = 0; c < 8; c++) {
            float bb = b1[c * 16 + l15];
            int col = c * 16 + l15;
#pragma unroll
            for (int r = 0; r < 4; r++) {
                int row = rowb + lhi * 4 + r;
                float v = fmaxf(acc[c][r] + bb, 0.f);
                bfp16 bv = __float2bfloat16(v);
                sA[row * 128 + ((((col >> 3)) ^ (row & 7)) << 3) + (col & 7)] =
                    *reinterpret_cast<short*>(&bv);
            }
        }
    }
    __syncthreads();

    f32x4 acc2[8];
#pragma unroll
    for (int c = 0; c < 8; c++) acc2[c] = (f32x4){0.f, 0.f, 0.f, 0.f};
#pragma unroll
    for (int kk = 0; kk < 4; kk++) {
        int kslot = kk * 4 + lhi;
        s16x8 af = *(const s16x8*)&sA[abase + ((kslot ^ asw) << 3)];
#pragma unroll
        for (int c = 0; c < 8; c++) {
            s16x8 bfr = *(const s16x8*)&sW2[(c * 16 + l15) * 128 + ((kslot ^ bsw) << 3)];
            acc2[c] = __builtin_amdgcn_mfma_f32_16x16x32_bf16(af, bfr, acc2[c], 0, 0, 0);
        }
    }

    const int rb = rowBase + (w << 4) + lhi * 4;
    float scol[8], qcol[8];
#pragma unroll
    for (int c = 0; c < 8; c++) {
        float bb = b2[c * 16 + l15];
        float s = 0.f, q = 0.f;
#pragma unroll
        for (int r = 0; r < 4; r++) {
            int row = rb + r;
            float v = acc2[c][r] + bb;
            if (row < N) {
                z2[(size_t)row * 128 + c * 16 + l15] = __float2bfloat16(v);
                s += v;
                q += v * v;
            }
        }
        scol[c] = s;
        qcol[c] = q;
    }
#pragma unroll
    for (int c = 0; c < 8; c++) {
        scol[c] += __shfl_xor(scol[c], 16);
        scol[c] += __shfl_xor(scol[c], 32);
        qcol[c] += __shfl_xor(qcol[c], 16);
        qcol[c] += __shfl_xor(qcol[c], 32);
    }
    __syncthreads();
    float* sStat = (float*)sA;
    if (lane < 16) {
#pragma unroll
        for (int c = 0; c < 8; c++) {
            sStat[w * 256 + c * 16 + lane] = scol[c];
            sStat[w * 256 + 128 + c * 16 + lane] = qcol[c];
        }
    }
    __syncthreads();
    if (t < 128) {
        float ss = sStat[t] + sStat[256 + t] + sStat[512 + t] + sStat[768 + t];
        float qq = sStat[128 + t] + sStat[384 + t] + sStat[640 + t] + sStat[896 + t];
        atomicAdd(&stats[t], ss);
        atomicAdd(&stats[128 + t], qq);
    }
}

// ---------------- final: BN(z2) -> per-graph mean pool -> dot --------------
__global__ __launch_bounds__(256) void k_finalpool(const bfp16* __restrict__ z2,
                                                   const float* __restrict__ stats,
                                                   const float* __restrict__ gamma,
                                                   const float* __restrict__ beta,
                                                   const int* __restrict__ batch,
                                                   const float* __restrict__ mol,
                                                   const float* __restrict__ Wf,
                                                   const float* __restrict__ bfp,
                                                   float* __restrict__ out) {
    int gid = (blockIdx.x * blockDim.x + threadIdx.x) >> 6;
    int lane = threadIdx.x & 63;
    if (gid >= NG) return;
    const int f = lane * 2;

    const float invn = 1.f / NN;
    float m0 = stats[f] * invn;
    float v0 = stats[128 + f] * invn - m0 * m0;
    float sc0 = rsqrtf(v0 + BN_EPS) * gamma[f];
    float sf0 = beta[f] - m0 * sc0;
    float m1 = stats[f + 1] * invn;
    float v1 = stats[128 + f + 1] * invn - m1 * m1;
    float sc1 = rsqrtf(v1 + BN_EPS) * gamma[f + 1];
    float sf1 = beta[f + 1] - m1 * sc1;

    int lo = 0, hi = NN;
    while (lo < hi) { int m = (lo + hi) >> 1; if (batch[m] < gid) lo = m + 1; else hi = m; }
    int lb = lo;
    hi = NN;
    while (lo < hi) { int m = (lo + hi) >> 1; if (batch[m] <= gid) lo = m + 1; else hi = m; }
    int cnt = lo - lb;

    float sx = 0.f, sy = 0.f;
    for (int n = lb; n < lo; n++) {
        float2 v = __bfloat1622float2(*(const bfp162*)&z2[(size_t)n * HID + f]);
        sx += fmaxf(v.x * sc0 + sf0, 0.f);
        sy += fmaxf(v.y * sc1 + sf1, 0.f);
    }
    float inv = 1.f / fmaxf((float)cnt, 1.f);
    float acc = sx * inv * Wf[f] + sy * inv * Wf[f + 1];
    if (lane < DESCD) acc += mol[(size_t)gid * DESCD + lane] * Wf[HID + lane];
#pragma unroll
    for (int o = 32; o > 0; o >>= 1) acc += __shfl_down(acc, o);
    if (lane == 0) out[gid] = acc + bfp[0];
}

extern "C" void kernel_launch(void* const* d_in, const int* in_sizes, int n_in,
                              void* d_out, int out_size, void* d_ws, size_t ws_size,
                              hipStream_t stream) {
    const float* x     = (const float*)d_in[0];
    const int*   ei    = (const int*)d_in[1];
    const float* ea    = (const float*)d_in[2];
    const int*   batch = (const int*)d_in[3];
    const float* mol   = (const float*)d_in[4];
    const float* Wp    = (const float*)d_in[5];
    const float* bp    = (const float*)d_in[6];
    const float* W1    = (const float*)d_in[7];
    const float* b1    = (const float*)d_in[8];
    const float* W2    = (const float*)d_in[9];
    const float* b2    = (const float*)d_in[10];
    const float* gamma = (const float*)d_in[11];
    const float* beta  = (const float*)d_in[12];
    const float* Wf    = (const float*)d_in[13];
    const float* bf_   = (const float*)d_in[14];
    float* out = (float*)d_out;

    char* p = (char*)d_ws;
    size_t off = 0;
    auto alloc = [&](size_t bytes) {
        char* q = p + off;
        off = (off + bytes + 255) & ~(size_t)255;
        return q;
    };
    bfp16* h      = (bfp16*)alloc((size_t)NN * HID * 2);
    bfp16* z      = (bfp16*)alloc((size_t)NN * HID * 2);
    bfp16* z2     = (bfp16*)alloc((size_t)NN * HID * 2);
    bfp16* Wt     = (bfp16*)alloc((size_t)6 * HID * HID * 2);
    int2*  perm   = (int2*)alloc((size_t)NE * 8);
    int*   rowptr = (int*)alloc((NN + 16) * 4);
    int*   cursor = (int*)alloc(NN * 4);
    int*   partials = (int*)alloc(NB_SCAN * 4);
    int*   poffs    = (int*)alloc(NB_SCAN * 4);
    // contiguous zero-init region: deg | stats3
    size_t zoff = off;
    int*   deg    = (int*)alloc(NN * 4);
    float* stats3 = (float*)alloc(3 * 256 * 4);
    size_t zlen = off - zoff;
    bfp16* eab    = (bfp16*)alloc((size_t)NE * HID * 2);

    const int* src = ei;
    const int* dst = ei + NE;

    (void)hipMemsetAsync(p + zoff, 0, zlen, stream);
    k_hist<<<(NE + 255) / 256, 256, 0, stream>>>(dst, deg);
    k_part<<<NB_SCAN, 256, 0, stream>>>(deg, partials);
    k_scanpart<<<1, 256, 0, stream>>>(partials, poffs);
    k_scatter<<<NB_SCAN, 256, 0, stream>>>(deg, poffs, rowptr, cursor);
    k_fill<<<(NE + 255) / 256, 256, 0, stream>>>(src, dst, cursor, perm);
    k_prep<<<9600000 / 256, 256, 0, stream>>>(ea, eab, x, Wp, bp, h, W1, W2, Wt);

    const int aggrGrid = (NN * 64) / 256;
    const int mlpGrid = (NN + 63) / 64;
    for (int l = 0; l < NL; l++) {
        if (l == 0)
            k_aggr<false><<<aggrGrid, 256, 0, stream>>>(
                h, eab, perm, rowptr, nullptr, nullptr, nullptr, z);
        else
            k_aggr<true><<<aggrGrid, 256, 0, stream>>>(
                z2, eab, perm, rowptr, stats3 + (l - 1) * 256,
                gamma + (l - 1) * HID, beta + (l - 1) * HID, z);
        k_mlp<<<mlpGrid, 256, 0, stream>>>(
            z, Wt + (size_t)l * HID * HID, Wt + (size_t)(3 + l) * HID * HID,
            b1 + l * HID, b2 + l * HID, z2, stats3 + l * 256, NN);
    }

    k_finalpool<<<(NG * 64) / 256, 256, 0, stream>>>(
        z2, stats3 + 2 * 256, gamma + 2 * HID, beta + 2 * HID,
        batch, mol, Wf, bf_, out);
}

// Round 14
// 431.551 us; speedup vs baseline: 4.1101x; 1.0606x over previous
//
#include <hip/hip_runtime.h>
#include <hip/hip_bf16.h>

#define NN 50000
#define NE 600000
#define NG 1000
#define IND 16
#define HID 128
#define DESCD 17
#define NL 3
#define BN_EPS 1e-5f
#define NB_SCAN 196  // ceil(NN/256)

typedef short s16x8 __attribute__((ext_vector_type(8)));
typedef float f32x4 __attribute__((ext_vector_type(4)));
typedef int   i32x4 __attribute__((ext_vector_type(4)));
typedef __hip_bfloat16 bfp16;
typedef __hip_bfloat162 bfp162;

__device__ __forceinline__ float b2f(short s) {
    return __uint_as_float(((unsigned int)(unsigned short)s) << 16);
}

// ---------------- CSR build (5 small dispatches; NO grid.sync) -------------
__global__ __launch_bounds__(256) void k_hist(const int* __restrict__ dst,
                                              int* __restrict__ deg) {
    int e = blockIdx.x * blockDim.x + threadIdx.x;
    if (e >= NE) return;
    atomicAdd(&deg[dst[e]], 1);
}

__global__ __launch_bounds__(256) void k_part(const int* __restrict__ deg,
                                              int* __restrict__ partials) {
    __shared__ int sh[256];
    int i = blockIdx.x * 256 + threadIdx.x;
    sh[threadIdx.x] = (i < NN) ? deg[i] : 0;
    __syncthreads();
    for (int o = 128; o > 0; o >>= 1) {
        if (threadIdx.x < o) sh[threadIdx.x] += sh[threadIdx.x + o];
        __syncthreads();
    }
    if (threadIdx.x == 0) partials[blockIdx.x] = sh[0];
}

__global__ __launch_bounds__(256) void k_scanpart(const int* __restrict__ partials,
                                                  int* __restrict__ poffs) {
    __shared__ int sh[256];
    int t = threadIdx.x;
    int v = (t < NB_SCAN) ? partials[t] : 0;
    sh[t] = v;
    __syncthreads();
    for (int o = 1; o < 256; o <<= 1) {
        int tmp = (t >= o) ? sh[t - o] : 0;
        __syncthreads();
        sh[t] += tmp;
        __syncthreads();
    }
    if (t < NB_SCAN) poffs[t] = sh[t] - v;
}

__global__ __launch_bounds__(256) void k_scatter(const int* __restrict__ deg,
                                                 const int* __restrict__ poffs,
                                                 int* __restrict__ rowptr,
                                                 int* __restrict__ cursor) {
    __shared__ int sh[256];
    int b = blockIdx.x, t = threadIdx.x;
    int i = b * 256 + t;
    int v = (i < NN) ? deg[i] : 0;
    sh[t] = v;
    __syncthreads();
    for (int o = 1; o < 256; o <<= 1) {
        int tmp = (t >= o) ? sh[t - o] : 0;
        __syncthreads();
        sh[t] += tmp;
        __syncthreads();
    }
    int excl = sh[t] - v + poffs[b];
    if (i < NN) {
        rowptr[i] = excl;
        cursor[i] = excl;
        if (i == NN - 1) rowptr[NN] = excl + v;
    }
}

__global__ __launch_bounds__(256) void k_fill(const int* __restrict__ src,
                                              const int* __restrict__ dst,
                                              int* __restrict__ cursor,
                                              int2* __restrict__ perm) {
    int e = blockIdx.x * blockDim.x + threadIdx.x;
    if (e >= NE) return;
    int pos = atomicAdd(&cursor[dst[e]], 1);
    perm[pos] = make_int2(e, src[e]);
}

// ---------------- fused proj + weight prep ----------------
__global__ __launch_bounds__(256) void k_projwprep(const float* __restrict__ x,
                                                   const float* __restrict__ Wp,
                                                   const float* __restrict__ bp,
                                                   bfp16* __restrict__ h,
                                                   const float* __restrict__ W1,
                                                   const float* __restrict__ W2,
                                                   bfp16* __restrict__ Wt,
                                                   int projBlocks) {
    if (blockIdx.x < (unsigned)projBlocks) {
        int idx = blockIdx.x * blockDim.x + threadIdx.x;
        if (idx >= NN * HID) return;
        int row = idx >> 7, col = idx & 127;
        const float* xr = x + (size_t)row * IND;
        float acc = bp[col];
#pragma unroll
        for (int k = 0; k < IND; k++) acc += xr[k] * Wp[k * HID + col];
        h[idx] = __float2bfloat16(acc);
    } else {
        int id = (blockIdx.x - projBlocks) * blockDim.x + threadIdx.x;
        if (id >= 6 * HID * HID) return;
        int m = id >> 14;
        int rem = id & 16383;
        int n = rem >> 7, k = rem & 127;
        const float* Wsrc = (m < 3) ? (W1 + (size_t)m * HID * HID)
                                    : (W2 + (size_t)(m - 3) * HID * HID);
        Wt[id] = __float2bfloat16(Wsrc[k * HID + n]);
    }
}

// ---------------- gather aggregation, 4 edges/wave, 16B/lane ---------------
// z[n] = H(n) + sum_e relu(H(src)+e);  H(v) = BN? relu(hz*sc+sf) : hz
// wave = 4 slots x 16 lanes; lane owns 8 cols (c0..c0+7) of its slot's edge.
// eab is stored in CSR ORDER (index i). MODE 1: read ea f32 via perm.x, write
// eab at i. MODE 2: read eab linearly at i.
template <int MODE, bool BN>
__global__ __launch_bounds__(256) void k_aggr(const bfp16* __restrict__ hz,
                                              const float* __restrict__ ea,
                                              bfp16* __restrict__ eab,
                                              const int2* __restrict__ perm,
                                              const int* __restrict__ rowptr,
                                              const float* __restrict__ stats,
                                              const float* __restrict__ gamma,
                                              const float* __restrict__ beta,
                                              bfp16* __restrict__ z) {
    int nid = (blockIdx.x * blockDim.x + threadIdx.x) >> 6;
    int lane = threadIdx.x & 63;
    if (nid >= NN) return;
    const int slot = lane >> 4;
    const int c0 = (lane & 15) << 3;

    float sc[8], sf[8];
    if (BN) {
        const float invn = 1.f / NN;
#pragma unroll
        for (int j = 0; j < 8; j++) {
            int c = c0 + j;
            float m = stats[c] * invn;
            float v = stats[128 + c] * invn - m * m;
            sc[j] = rsqrtf(v + BN_EPS) * gamma[c];
            sf[j] = beta[c] - m * sc[j];
        }
    }

    float acc[8];
#pragma unroll
    for (int j = 0; j < 8; j++) acc[j] = 0.f;

    auto body = [&](int i) {
        int2 pr = perm[i];
        float a[8];
        if (MODE == 1) {
            f32x4 a0 = __builtin_nontemporal_load(
                (const f32x4*)&ea[(size_t)pr.x * HID + c0]);
            f32x4 a1 = __builtin_nontemporal_load(
                (const f32x4*)&ea[(size_t)pr.x * HID + c0 + 4]);
            a[0] = a0.x; a[1] = a0.y; a[2] = a0.z; a[3] = a0.w;
            a[4] = a1.x; a[5] = a1.y; a[6] = a1.z; a[7] = a1.w;
            bfp162 p0 = __float22bfloat162_rn(make_float2(a[0], a[1]));
            bfp162 p1 = __float22bfloat162_rn(make_float2(a[2], a[3]));
            bfp162 p2 = __float22bfloat162_rn(make_float2(a[4], a[5]));
            bfp162 p3 = __float22bfloat162_rn(make_float2(a[6], a[7]));
            i32x4 o;
            o.x = *reinterpret_cast<int*>(&p0);
            o.y = *reinterpret_cast<int*>(&p1);
            o.z = *reinterpret_cast<int*>(&p2);
            o.w = *reinterpret_cast<int*>(&p3);
            *(i32x4*)&eab[(size_t)i * HID + c0] = o;
        } else {
            s16x8 av = *(const s16x8*)&eab[(size_t)i * HID + c0];  // CSR-linear
#pragma unroll
            for (int j = 0; j < 8; j++) a[j] = b2f(av[j]);
        }
        s16x8 hv = *(const s16x8*)&hz[(size_t)pr.y * HID + c0];
#pragma unroll
        for (int j = 0; j < 8; j++) {
            float hf = b2f(hv[j]);
            if (BN) hf = fmaxf(hf * sc[j] + sf[j], 0.f);
            acc[j] += fmaxf(a[j] + hf, 0.f);
        }
    };

    int beg = rowptr[nid], end = rowptr[nid + 1];
    int i = beg + slot;
    for (; i + 4 < end; i += 8) {
        body(i);
        body(i + 4);
    }
    if (i < end) body(i);

#pragma unroll
    for (int j = 0; j < 8; j++) {
        acc[j] += __shfl_xor(acc[j], 16);
        acc[j] += __shfl_xor(acc[j], 32);
    }

    if (lane < 16) {
        s16x8 hv = *(const s16x8*)&hz[(size_t)nid * HID + c0];
        bfp162 pk[4];
#pragma unroll
        for (int j = 0; j < 4; j++) {
            float h0 = b2f(hv[2 * j]);
            float h1 = b2f(hv[2 * j + 1]);
            if (BN) {
                h0 = fmaxf(h0 * sc[2 * j] + sf[2 * j], 0.f);
                h1 = fmaxf(h1 * sc[2 * j + 1] + sf[2 * j + 1], 0.f);
            }
            pk[j] = __float22bfloat162_rn(make_float2(acc[2 * j] + h0,
                                                      acc[2 * j + 1] + h1));
        }
        i32x4 o;
        o.x = *reinterpret_cast<int*>(&pk[0]);
        o.y = *reinterpret_cast<int*>(&pk[1]);
        o.z = *reinterpret_cast<int*>(&pk[2]);
        o.w = *reinterpret_cast<int*>(&pk[3]);
        *(i32x4*)&z[(size_t)nid * HID + c0] = o;
    }
}

// ---------------- fused MLP: z2 = relu(A@W1+b1)@W2+b2, + BN col sums -------
__global__ __launch_bounds__(256) void k_mlp(const bfp16* __restrict__ A,
                                             const bfp16* __restrict__ Wt1,
                                             const bfp16* __restrict__ Wt2,
                                             const float* __restrict__ b1,
                                             const float* __restrict__ b2,
                                             bfp16* __restrict__ z2,
                                             float* __restrict__ stats,
                                             int N) {
    __shared__ __align__(16) short sW1[128 * 128];
    __shared__ __align__(16) short sW2[128 * 128];
    __shared__ __align__(16) short sA[64 * 128];
    const int t = threadIdx.x;
    const int rowBase = blockIdx.x * 64;

    const short* W1g = (const short*)Wt1;
    const short* W2g = (const short*)Wt2;
    for (int g = t; g < 2048; g += 256) {
        int nrow = g >> 4, s = g & 15;
        int sw = nrow * 128 + ((s ^ (nrow & 7)) << 3);
        *(float4*)&sW1[sw] = *(const float4*)&W1g[g * 8];
        *(float4*)&sW2[sw] = *(const float4*)&W2g[g * 8];
    }
    const short* Ag = (const short*)A;
    for (int g = t; g < 1024; g += 256) {
        int r = g >> 4, s = g & 15;
        float4 v = make_float4(0.f, 0.f, 0.f, 0.f);
        if (rowBase + r < N) v = *(const float4*)&Ag[(size_t)(rowBase + r) * 128 + s * 8];
        *(float4*)&sA[r * 128 + ((s ^ (r & 7)) << 3)] = v;
    }
    __syncthreads();

    const int w = t >> 6, lane = t & 63;
    const int l15 = lane & 15, lhi = lane >> 4;
    const int arow = (w << 4) + l15;
    const int abase = arow * 128, asw = arow & 7;
    const int bsw = l15 & 7;

    f32x4 acc[8];
#pragma unroll
    for (int c = 0; c < 8; c++) acc[c] = (f32x4){0.f, 0.f, 0.f, 0.f};
#pragma unroll
    for (int kk = 0; kk < 4; kk++) {
        int kslot = kk * 4 + lhi;
        s16x8 af = *(const s16x8*)&sA[abase + ((kslot ^ asw) << 3)];
#pragma unroll
        for (int c = 0; c < 8; c++) {
            s16x8 bfr = *(const s16x8*)&sW1[(c * 16 + l15) * 128 + ((kslot ^ bsw) << 3)];
            acc[c] = __builtin_amdgcn_mfma_f32_16x16x32_bf16(af, bfr, acc[c], 0, 0, 0);
        }
    }
    __syncthreads();

    {
        const int rowb = (w << 4);
#pragma unroll
        for (int c = 0; c < 8; c++) {
            float bb = b1[c * 16 + l15];
            int col = c * 16 + l15;
#pragma unroll
            for (int r = 0; r < 4; r++) {
                int row = rowb + lhi * 4 + r;
                float v = fmaxf(acc[c][r] + bb, 0.f);
                bfp16 bv = __float2bfloat16(v);
                sA[row * 128 + ((((col >> 3)) ^ (row & 7)) << 3) + (col & 7)] =
                    *reinterpret_cast<short*>(&bv);
            }
        }
    }
    __syncthreads();

    f32x4 acc2[8];
#pragma unroll
    for (int c = 0; c < 8; c++) acc2[c] = (f32x4){0.f, 0.f, 0.f, 0.f};
#pragma unroll
    for (int kk = 0; kk < 4; kk++) {
        int kslot = kk * 4 + lhi;
        s16x8 af = *(const s16x8*)&sA[abase + ((kslot ^ asw) << 3)];
#pragma unroll
        for (int c = 0; c < 8; c++) {
            s16x8 bfr = *(const s16x8*)&sW2[(c * 16 + l15) * 128 + ((kslot ^ bsw) << 3)];
            acc2[c] = __builtin_amdgcn_mfma_f32_16x16x32_bf16(af, bfr, acc2[c], 0, 0, 0);
        }
    }

    const int rb = rowBase + (w << 4) + lhi * 4;
    float scol[8], qcol[8];
#pragma unroll
    for (int c = 0; c < 8; c++) {
        float bb = b2[c * 16 + l15];
        float s = 0.f, q = 0.f;
#pragma unroll
        for (int r = 0; r < 4; r++) {
            int row = rb + r;
            float v = acc2[c][r] + bb;
            if (row < N) {
                z2[(size_t)row * 128 + c * 16 + l15] = __float2bfloat16(v);
                s += v;
                q += v * v;
            }
        }
        scol[c] = s;
        qcol[c] = q;
    }
#pragma unroll
    for (int c = 0; c < 8; c++) {
        scol[c] += __shfl_xor(scol[c], 16);
        scol[c] += __shfl_xor(scol[c], 32);
        qcol[c] += __shfl_xor(qcol[c], 16);
        qcol[c] += __shfl_xor(qcol[c], 32);
    }
    __syncthreads();
    float* sStat = (float*)sA;
    if (lane < 16) {
#pragma unroll
        for (int c = 0; c < 8; c++) {
            sStat[w * 256 + c * 16 + lane] = scol[c];
            sStat[w * 256 + 128 + c * 16 + lane] = qcol[c];
        }
    }
    __syncthreads();
    if (t < 128) {
        float ss = sStat[t] + sStat[256 + t] + sStat[512 + t] + sStat[768 + t];
        float qq = sStat[128 + t] + sStat[384 + t] + sStat[640 + t] + sStat[896 + t];
        atomicAdd(&stats[t], ss);
        atomicAdd(&stats[128 + t], qq);
    }
}

// ---------------- final: BN(z2) -> per-graph mean pool -> dot --------------
__global__ __launch_bounds__(256) void k_finalpool(const bfp16* __restrict__ z2,
                                                   const float* __restrict__ stats,
                                                   const float* __restrict__ gamma,
                                                   const float* __restrict__ beta,
                                                   const int* __restrict__ batch,
                                                   const float* __restrict__ mol,
                                                   const float* __restrict__ Wf,
                                                   const float* __restrict__ bfp,
                                                   float* __restrict__ out) {
    int gid = (blockIdx.x * blockDim.x + threadIdx.x) >> 6;
    int lane = threadIdx.x & 63;
    if (gid >= NG) return;
    const int f = lane * 2;

    const float invn = 1.f / NN;
    float m0 = stats[f] * invn;
    float v0 = stats[128 + f] * invn - m0 * m0;
    float sc0 = rsqrtf(v0 + BN_EPS) * gamma[f];
    float sf0 = beta[f] - m0 * sc0;
    float m1 = stats[f + 1] * invn;
    float v1 = stats[128 + f + 1] * invn - m1 * m1;
    float sc1 = rsqrtf(v1 + BN_EPS) * gamma[f + 1];
    float sf1 = beta[f + 1] - m1 * sc1;

    int lo = 0, hi = NN;
    while (lo < hi) { int m = (lo + hi) >> 1; if (batch[m] < gid) lo = m + 1; else hi = m; }
    int lb = lo;
    hi = NN;
    while (lo < hi) { int m = (lo + hi) >> 1; if (batch[m] <= gid) lo = m + 1; else hi = m; }
    int cnt = lo - lb;

    float sx = 0.f, sy = 0.f;
    for (int n = lb; n < lo; n++) {
        float2 v = __bfloat1622float2(*(const bfp162*)&z2[(size_t)n * HID + f]);
        sx += fmaxf(v.x * sc0 + sf0, 0.f);
        sy += fmaxf(v.y * sc1 + sf1, 0.f);
    }
    float inv = 1.f / fmaxf((float)cnt, 1.f);
    float acc = sx * inv * Wf[f] + sy * inv * Wf[f + 1];
    if (lane < DESCD) acc += mol[(size_t)gid * DESCD + lane] * Wf[HID + lane];
#pragma unroll
    for (int o = 32; o > 0; o >>= 1) acc += __shfl_down(acc, o);
    if (lane == 0) out[gid] = acc + bfp[0];
}

extern "C" void kernel_launch(void* const* d_in, const int* in_sizes, int n_in,
                              void* d_out, int out_size, void* d_ws, size_t ws_size,
                              hipStream_t stream) {
    const float* x     = (const float*)d_in[0];
    const int*   ei    = (const int*)d_in[1];
    const float* ea    = (const float*)d_in[2];
    const int*   batch = (const int*)d_in[3];
    const float* mol   = (const float*)d_in[4];
    const float* Wp    = (const float*)d_in[5];
    const float* bp    = (const float*)d_in[6];
    const float* W1    = (const float*)d_in[7];
    const float* b1    = (const float*)d_in[8];
    const float* W2    = (const float*)d_in[9];
    const float* b2    = (const float*)d_in[10];
    const float* gamma = (const float*)d_in[11];
    const float* beta  = (const float*)d_in[12];
    const float* Wf    = (const float*)d_in[13];
    const float* bf_   = (const float*)d_in[14];
    float* out = (float*)d_out;

    char* p = (char*)d_ws;
    size_t off = 0;
    auto alloc = [&](size_t bytes) {
        char* q = p + off;
        off = (off + bytes + 255) & ~(size_t)255;
        return q;
    };
    bfp16* h      = (bfp16*)alloc((size_t)NN * HID * 2);
    bfp16* z      = (bfp16*)alloc((size_t)NN * HID * 2);
    bfp16* z2     = (bfp16*)alloc((size_t)NN * HID * 2);
    bfp16* Wt     = (bfp16*)alloc((size_t)6 * HID * HID * 2);
    int2*  perm   = (int2*)alloc((size_t)NE * 8);
    int*   rowptr = (int*)alloc((NN + 16) * 4);
    int*   cursor = (int*)alloc(NN * 4);
    int*   partials = (int*)alloc(NB_SCAN * 4);
    int*   poffs    = (int*)alloc(NB_SCAN * 4);
    // contiguous zero-init region: deg | stats3
    size_t zoff = off;
    int*   deg    = (int*)alloc(NN * 4);
    float* stats3 = (float*)alloc(3 * 256 * 4);
    size_t zlen = off - zoff;
    bfp16* eab    = (bfp16*)alloc((size_t)NE * HID * 2);

    const int* src = ei;
    const int* dst = ei + NE;

    (void)hipMemsetAsync(p + zoff, 0, zlen, stream);
    k_hist<<<(NE + 255) / 256, 256, 0, stream>>>(dst, deg);
    k_part<<<NB_SCAN, 256, 0, stream>>>(deg, partials);
    k_scanpart<<<1, 256, 0, stream>>>(partials, poffs);
    k_scatter<<<NB_SCAN, 256, 0, stream>>>(deg, poffs, rowptr, cursor);
    k_fill<<<(NE + 255) / 256, 256, 0, stream>>>(src, dst, cursor, perm);
    {
        const int projBlocks = (NN * HID) / 256;
        const int wprepBlocks = (6 * HID * HID + 255) / 256;
        k_projwprep<<<projBlocks + wprepBlocks, 256, 0, stream>>>(
            x, Wp, bp, h, W1, W2, Wt, projBlocks);
    }

    const int aggrGrid = (NN * 64) / 256;
    const int mlpGrid = (NN + 63) / 64;
    for (int l = 0; l < NL; l++) {
        if (l == 0)
            k_aggr<1, false><<<aggrGrid, 256, 0, stream>>>(
                h, ea, eab, perm, rowptr, nullptr, nullptr, nullptr, z);
        else
            k_aggr<2, true><<<aggrGrid, 256, 0, stream>>>(
                z2, nullptr, eab, perm, rowptr, stats3 + (l - 1) * 256,
                gamma + (l - 1) * HID, beta + (l - 1) * HID, z);
        k_mlp<<<mlpGrid, 256, 0, stream>>>(
            z, Wt + (size_t)l * HID * HID, Wt + (size_t)(3 + l) * HID * HID,
            b1 + l * HID, b2 + l * HID, z2, stats3 + l * 256, NN);
    }

    k_finalpool<<<(NG * 64) / 256, 256, 0, stream>>>(
        z2, stats3 + 2 * 256, gamma + 2 * HID, beta + 2 * HID,
        batch, mol, Wf, bf_, out);
}